// Round 6
// baseline (454.873 us; speedup 1.0000x reference)
//
#include <hip/hip_runtime.h>
#include <hip/hip_bf16.h>

#define N_NODES 16384
#define N_EDGES 65536
#define NB      32
#define H       64
#define NLAYERS 3
#define NEG     0.1f
#define LN_EPS  1e-5f

typedef _Float16 f16;
typedef _Float16 f16x2 __attribute__((ext_vector_type(2)));
typedef _Float16 f16x8 __attribute__((ext_vector_type(8)));
typedef __fp16   hf16x2 __attribute__((ext_vector_type(2)));
typedef float    f32x16 __attribute__((ext_vector_type(16)));

union F16x8 { f16x8 v; f16x2 p[4]; int4 i4; int2 i2[2]; };
union F16x2U { f16x2 h2; hf16x2 raw; unsigned int u; };
union F16U   { f16 h; unsigned short u; };

__device__ __forceinline__ f16x2 pkrtz(float a, float b) {
    F16x2U t; t.raw = __builtin_amdgcn_cvt_pkrtz(a, b); return t.h2;
}
__device__ __forceinline__ float leaky(float v) { return v > 0.f ? v : NEG * v; }

// ---------------------------------------------------------------- init: inproj + degree (fused)
__global__ __launch_bounds__(256) void k_init(const float* __restrict__ x,
                                              const float* __restrict__ Win,
                                              const float* __restrict__ bin,
                                              const int* __restrict__ dst,
                                              float* __restrict__ h,
                                              float* __restrict__ deg) {
    int bid = blockIdx.x;
    if (bid < 4096) {
        int t = bid * 256 + threadIdx.x;
        int n = t >> 6, j = t & 63;
        const float* xr = x + n * 4;
        const float* wr = Win + j * 4;
        float v = bin[j] + xr[0] * wr[0] + xr[1] * wr[1] + xr[2] * wr[2] + xr[3] * wr[3];
        h[t] = leaky(v);
    } else {
        int e = (bid - 4096) * 256 + threadIdx.x;
        atomicAdd(&deg[dst[e]], 1.0f);
    }
}

// ---------------------------------------------------------------- Bp (3 layers): MFMA-fragment f16 B
// slot = i*8 + ks*2 + oq (i in [0,64]; i==64 = eb3 bias). layer stride 520 slots.
__global__ __launch_bounds__(256) void k_prep_bp(const float* __restrict__ ew3,
                                                 const float* __restrict__ eb3,
                                                 f16* __restrict__ Bp) {
    int tg    = blockIdx.x * 256 + threadIdx.x;   // 390*256 = 1560 gslots * 64 lanes
    int lane  = tg & 63;
    int gslot = tg >> 6;
    int l     = gslot / 520;
    int slot  = gslot - l * 520;
    const float* ew3l = ew3 + (size_t)l * 262144;
    const float* eb3l = eb3 + (size_t)l * 4096;
    int i   = slot >> 3;
    int rem = slot & 7;
    int ks  = rem >> 1;
    int oq  = rem & 1;
    int o   = oq * 32 + (lane & 31);
    int k0  = ks * 16 + (lane >> 5) * 8;
    float v[8];
    if (i < 64) {
        const float* s = ew3l + ((size_t)(i * 64 + o)) * 64 + k0;
        float4 a = ((const float4*)s)[0];
        float4 b = ((const float4*)s)[1];
        v[0] = a.x; v[1] = a.y; v[2] = a.z; v[3] = a.w;
        v[4] = b.x; v[5] = b.y; v[6] = b.z; v[7] = b.w;
    } else {
#pragma unroll
        for (int j = 0; j < 8; j++) v[j] = eb3l[(k0 + j) * 64 + o];
    }
    union { int4 i4; f16 a[8]; } out;
#pragma unroll
    for (int j = 0; j < 8; j++) out.a[j] = (f16)v[j];
    *(int4*)(Bp + (size_t)l * 266240 + (size_t)slot * 512 + lane * 8) = out.i4;
}

// ---------------------------------------------------------------- edge MLP (MFMA stage2), f16 output
__global__ __launch_bounds__(256) void k_edge_mlp(const float* __restrict__ ea,
                                                  const float* __restrict__ w1,
                                                  const float* __restrict__ b1,
                                                  const float* __restrict__ w2,
                                                  const float* __restrict__ b2,
                                                  unsigned short* __restrict__ e2h) {
    __shared__ float eas[128 * 8];
    __shared__ __align__(16) unsigned short e1L[128 * 72];
    int t = threadIdx.x;
    int eb = blockIdx.x * 128;

    for (int idx = t; idx < 640; idx += 256) {
        int r = idx / 5, d = idx - r * 5;
        eas[r * 8 + d] = ea[(size_t)eb * 5 + idx];
    }
    __syncthreads();

    {
        int kk = t & 63;
        int eg = t >> 6;
        float w1r[5];
#pragma unroll
        for (int d = 0; d < 5; d++) w1r[d] = w1[kk * 5 + d];
        float b1r = b1[kk];
        for (int g = 0; g < 32; g++) {
            int row = g * 4 + eg;
            float4 a4 = *(const float4*)(eas + row * 8);
            float a5 = eas[row * 8 + 4];
            float v = b1r + a4.x * w1r[0] + a4.y * w1r[1] + a4.z * w1r[2] + a4.w * w1r[3] + a5 * w1r[4];
            F16U z; z.h = (f16)leaky(v);
            e1L[row * 72 + kk] = z.u;
        }
    }
    __syncthreads();

    int lane = t & 63;
    int w    = t >> 6;
    int eq2  = w >> 1, oq = w & 1;
    int m    = lane & 31;
    int kp   = lane >> 5;

    F16x8 Bf[4];
#pragma unroll
    for (int ks = 0; ks < 4; ks++) {
        const float* s = w2 + (size_t)(oq * 32 + m) * 64 + ks * 16 + kp * 8;
        float4 a = ((const float4*)s)[0];
        float4 b = ((const float4*)s)[1];
        Bf[ks].p[0] = pkrtz(a.x, a.y);
        Bf[ks].p[1] = pkrtz(a.z, a.w);
        Bf[ks].p[2] = pkrtz(b.x, b.y);
        Bf[ks].p[3] = pkrtz(b.z, b.w);
    }
    float b2r = b2[oq * 32 + m];

    f32x16 C0 = {0,0,0,0,0,0,0,0,0,0,0,0,0,0,0,0};
    f32x16 C1 = {0,0,0,0,0,0,0,0,0,0,0,0,0,0,0,0};
#pragma unroll
    for (int ks = 0; ks < 4; ks++) {
        int koff = (ks * 16 + kp * 8);
        F16x8 A0, A1;
        A0.i4 = *(const int4*)(e1L + (size_t)(eq2 * 64 + m) * 72 + koff);
        A1.i4 = *(const int4*)(e1L + (size_t)(eq2 * 64 + 32 + m) * 72 + koff);
        C0 = __builtin_amdgcn_mfma_f32_32x32x16_f16(A0.v, Bf[ks].v, C0, 0, 0, 0);
        C1 = __builtin_amdgcn_mfma_f32_32x32x16_f16(A1.v, Bf[ks].v, C1, 0, 0, 0);
    }

    int o = oq * 32 + m;
#pragma unroll
    for (int reg = 0; reg < 16; reg++) {
        int r = (reg & 3) + 8 * (reg >> 2) + 4 * kp;
        F16U z; z.h = (f16)leaky(C0[reg] + b2r);
        e2h[(size_t)(eb + eq2 * 64 + r) * 64 + o] = z.u;
    }
#pragma unroll
    for (int reg = 0; reg < 16; reg++) {
        int r = (reg & 3) + 8 * (reg >> 2) + 4 * kp;
        F16U z; z.h = (f16)leaky(C1[reg] + b2r);
        e2h[(size_t)(eb + eq2 * 64 + 32 + r) * 64 + o] = z.u;
    }
}

// ---------------------------------------------------------------- fused bilinear MFMA GEMM + scatter
// block = 256 edges, 4 waves; wave (eh, oq) handles 4 edge-tiles (eh*128..+127) x 32 outputs.
#define HS_STRIDE 76   // u16; 152 B rows -> lane stride 38 dwords, 2-way banks (free)

__device__ __forceinline__ void loadB8(const f16* __restrict__ Bp, int c, int oq, int lane, F16x8* dstB) {
    const f16* base = Bp + (((size_t)(c * 16 + oq)) << 9) + lane * 8;
#pragma unroll
    for (int di = 0; di < 2; di++)
#pragma unroll
        for (int ks = 0; ks < 4; ks++)
            dstB[di * 4 + ks].i4 = *(const int4*)(base + ((di * 8 + ks * 2) << 9));
}
__device__ __forceinline__ void loadB4(const f16* __restrict__ Bp, int oq, int lane, F16x8* dstB) {
    const f16* base = Bp + (((size_t)(512 + oq)) << 9) + lane * 8;
#pragma unroll
    for (int ks = 0; ks < 4; ks++)
        dstB[ks].i4 = *(const int4*)(base + ((ks * 2) << 9));
}

__global__ __launch_bounds__(256, 1) void k_msg(const float* __restrict__ h,
                                                const unsigned int* __restrict__ e2h,
                                                const f16* __restrict__ Bp,
                                                const int* __restrict__ src,
                                                const int* __restrict__ dst,
                                                float* __restrict__ agg) {
    __shared__ __align__(16) unsigned short hsL[256 * HS_STRIDE];  // 38.9 KB
    __shared__ int dstL[256];

    const int t    = threadIdx.x;
    const int lane = t & 63;
    const int w    = t >> 6;
    const int eh   = w >> 1, oq = w & 1;   // wave: edges eh*128..+127, outputs oq*32..+31
    const int m    = lane & 31;
    const int kp   = lane >> 5;
    const int eb   = blockIdx.x * 256;

    // ---- stage h rows (gathered by src, fp32 -> f16): thread t owns row t
    {
        int nsrc = src[eb + t];
        const float4* hr = (const float4*)(h + (size_t)nsrc * 64);
        unsigned int* hrow = (unsigned int*)hsL + t * (HS_STRIDE / 2);
#pragma unroll
        for (int q = 0; q < 16; q++) {
            float4 v = hr[q];
            F16x2U p0, p1;
            p0.raw = __builtin_amdgcn_cvt_pkrtz(v.x, v.y);
            p1.raw = __builtin_amdgcn_cvt_pkrtz(v.z, v.w);
            hrow[q * 2 + 0] = p0.u;
            hrow[q * 2 + 1] = p1.u;
        }
        dstL[t] = dst[eb + t];
    }

    // ---- e2 rows (f16 pairs) for this wave's 4 edge-tiles: 64 VGPRs
    f16x2 e2p[4][4][4];
#pragma unroll
    for (int tt = 0; tt < 4; tt++) {
        const unsigned int* row = e2h + (size_t)(eb + (eh * 4 + tt) * 32 + m) * 32;
#pragma unroll
        for (int ks = 0; ks < 4; ks++) {
            int4 q = *(const int4*)(row + ks * 8 + kp * 4);
            F16x2U u0, u1, u2, u3;
            u0.u = q.x; u1.u = q.y; u2.u = q.z; u3.u = q.w;
            e2p[tt][ks][0] = u0.h2; e2p[tt][ks][1] = u1.h2;
            e2p[tt][ks][2] = u2.h2; e2p[tt][ks][3] = u3.h2;
        }
    }
    __syncthreads();

    f32x16 C[4];
#pragma unroll
    for (int tt = 0; tt < 4; tt++)
#pragma unroll
        for (int r = 0; r < 16; r++) C[tt][r] = 0.f;

    const unsigned short* hp[4];
#pragma unroll
    for (int tt = 0; tt < 4; tt++)
        hp[tt] = hsL + ((eh * 4 + tt) * 32 + m) * HS_STRIDE;

    // ---- barrier-free K-loop: 2-buffer register pipeline, 1-chunk (~1000 cyc) coverage
    F16x8 B0[8], B1[8];
    loadB8(Bp, 0, oq, lane, B0);
    loadB8(Bp, 1, oq, lane, B1);

    for (int c = 0; c < 32; c++) {
        F16x8* cur = (c & 1) ? B1 : B0;
        unsigned int rr[4];
#pragma unroll
        for (int tt = 0; tt < 4; tt++) rr[tt] = *(const unsigned int*)(hp[tt] + 2 * c);
#pragma unroll
        for (int di = 0; di < 2; di++) {
            unsigned int sel = di ? 0x03020302u : 0x01000100u;
            F16x2U hh[4];
#pragma unroll
            for (int tt = 0; tt < 4; tt++) hh[tt].u = __builtin_amdgcn_perm(rr[tt], rr[tt], sel);
#pragma unroll
            for (int ks = 0; ks < 4; ks++) {
#pragma unroll
                for (int tt = 0; tt < 4; tt++) {
                    F16x8 A;
#pragma unroll
                    for (int r = 0; r < 4; r++) A.p[r] = hh[tt].h2 * e2p[tt][ks][r];
                    C[tt] = __builtin_amdgcn_mfma_f32_32x32x16_f16(A.v, cur[di * 4 + ks].v, C[tt], 0, 0, 0);
                }
            }
        }
        if (c + 2 < 32) loadB8(Bp, c + 2, oq, lane, cur);   // refill consumed buffer
    }

    // ---- bias chunk: A = h itself (k plays the i role), B = eb3 frags
    loadB4(Bp, oq, lane, B0);
#pragma unroll
    for (int ks = 0; ks < 4; ks++) {
        int koff = (ks * 16 + kp * 8) * 2;
#pragma unroll
        for (int tt = 0; tt < 4; tt++) {
            const char* rp = (const char*)hsL + (size_t)((eh * 4 + tt) * 32 + m) * (HS_STRIDE * 2) + koff;
            F16x8 A;
            A.i2[0] = *(const int2*)(rp); A.i2[1] = *(const int2*)(rp + 8);
            C[tt] = __builtin_amdgcn_mfma_f32_32x32x16_f16(A.v, B0[ks].v, C[tt], 0, 0, 0);
        }
    }

    // ---- scatter epilogue: C/D layout col=m, row=(reg&3)+8*(reg>>2)+4*kp
    int o = oq * 32 + m;
#pragma unroll
    for (int tt = 0; tt < 4; tt++) {
#pragma unroll
        for (int reg = 0; reg < 16; reg++) {
            int r = (reg & 3) + 8 * (reg >> 2) + 4 * kp;
            atomicAdd(&agg[(size_t)dstL[(eh * 4 + tt) * 32 + r] * 64 + o], C[tt][reg]);
        }
    }
}

// ---------------------------------------------------------------- node update: MFMA root GEMM + LN + residual (+pool on last)
__global__ __launch_bounds__(256) void k_node(const float* __restrict__ agg,
                                              const float* __restrict__ deg,
                                              const float* __restrict__ rw,
                                              const float* __restrict__ rb,
                                              const float* __restrict__ lg,
                                              const float* __restrict__ lb,
                                              float* __restrict__ h,
                                              const int* __restrict__ batch,
                                              float* __restrict__ pooled,
                                              int last) {
    __shared__ __align__(16) unsigned short hA[64 * 72];
    __shared__ float outL[64][68];
    int t = threadIdx.x;
    int nb = blockIdx.x * 64;
    int lane = t & 63, w = t >> 6;
    int nq = w >> 1, oq = w & 1;
    int m = lane & 31, kp = lane >> 5;

    {
        int r = t >> 2, c0 = (t & 3) * 16;
        const float4* hr = (const float4*)(h + (size_t)(nb + r) * 64 + c0);
        unsigned int* drow = (unsigned int*)hA + r * 36 + c0 / 2;
#pragma unroll
        for (int q = 0; q < 4; q++) {
            float4 v = hr[q];
            F16x2U p0, p1;
            p0.raw = __builtin_amdgcn_cvt_pkrtz(v.x, v.y);
            p1.raw = __builtin_amdgcn_cvt_pkrtz(v.z, v.w);
            drow[q * 2] = p0.u; drow[q * 2 + 1] = p1.u;
        }
    }
    F16x8 Bf[4];
#pragma unroll
    for (int ks = 0; ks < 4; ks++) {
        const float* s = rw + (size_t)(oq * 32 + m) * 64 + ks * 16 + kp * 8;
        float4 a = ((const float4*)s)[0];
        float4 b = ((const float4*)s)[1];
        Bf[ks].p[0] = pkrtz(a.x, a.y);
        Bf[ks].p[1] = pkrtz(a.z, a.w);
        Bf[ks].p[2] = pkrtz(b.x, b.y);
        Bf[ks].p[3] = pkrtz(b.z, b.w);
    }
    __syncthreads();

    f32x16 C = {0,0,0,0,0,0,0,0,0,0,0,0,0,0,0,0};
#pragma unroll
    for (int ks = 0; ks < 4; ks++) {
        F16x8 A;
        A.i4 = *(const int4*)(hA + (size_t)(nq * 32 + m) * 72 + ks * 16 + kp * 8);
        C = __builtin_amdgcn_mfma_f32_32x32x16_f16(A.v, Bf[ks].v, C, 0, 0, 0);
    }

    int o = oq * 32 + m;
#pragma unroll
    for (int reg = 0; reg < 16; reg++) {
        int r = (reg & 3) + 8 * (reg >> 2) + 4 * kp;
        int n = nq * 32 + r;
        outL[n][o] = C[reg] + rb[o] + agg[(size_t)(nb + n) * 64 + o] / fmaxf(deg[nb + n], 1.0f);
    }
    __syncthreads();

    float gj = lg[lane], bj = lb[lane];
    float accp = 0.f;
    int cur = batch[nb + w * 16];
    for (int q = 0; q < 16; q++) {
        int n = w * 16 + q;
        float v = outL[n][lane];
        float mu = v;
#pragma unroll
        for (int msk = 32; msk > 0; msk >>= 1) mu += __shfl_xor(mu, msk);
        mu *= (1.f / 64.f);
        float d = v - mu;
        float var = d * d;
#pragma unroll
        for (int msk = 32; msk > 0; msk >>= 1) var += __shfl_xor(var, msk);
        var *= (1.f / 64.f);
        float ov = d * rsqrtf(var + LN_EPS) * gj + bj;
        float hn = leaky(ov) + h[(size_t)(nb + n) * 64 + lane];
        h[(size_t)(nb + n) * 64 + lane] = hn;
        if (last) {
            int b = batch[nb + n];
            if (b != cur) { atomicAdd(&pooled[cur * 64 + lane], accp); accp = 0.f; cur = b; }
            accp += hn;
        }
    }
    if (last) atomicAdd(&pooled[cur * 64 + lane], accp);
}

// ---------------------------------------------------------------- prediction head (1 block; computes cnt from sorted batch)
__global__ __launch_bounds__(256) void k_head(const float* __restrict__ pooled,
                                              const int* __restrict__ batch,
                                              const float* __restrict__ pw1, const float* __restrict__ pb1,
                                              const float* __restrict__ pw2, const float* __restrict__ pb2,
                                              const float* __restrict__ pw3, const float* __restrict__ pb3,
                                              float* __restrict__ out) {
    __shared__ float cntL[32];
    __shared__ float ps[32][64];
    __shared__ float p1[32][64];
    __shared__ float p2[32][32];
    int t = threadIdx.x;
    if (t < 32) cntL[t] = 0.f;
    __syncthreads();
    {
        const int4* bp4 = (const int4*)(batch + t * 64);
        int cur = batch[t * 64];
        float c = 0.f;
        for (int q = 0; q < 16; q++) {
            int4 b4 = bp4[q];
            int bs[4] = { b4.x, b4.y, b4.z, b4.w };
#pragma unroll
            for (int e = 0; e < 4; e++) {
                if (bs[e] != cur) { atomicAdd(&cntL[cur], c); cur = bs[e]; c = 0.f; }
                c += 1.f;
            }
        }
        atomicAdd(&cntL[cur], c);
    }
    __syncthreads();
    for (int idx = t; idx < 2048; idx += 256) {
        int b = idx >> 6, j = idx & 63;
        ps[b][j] = pooled[idx] / fmaxf(cntL[b], 1.0f);
    }
    __syncthreads();
    for (int idx = t; idx < 2048; idx += 256) {
        int b = idx >> 6, j = idx & 63;
        float v = pb1[j];
#pragma unroll 8
        for (int i = 0; i < 64; i++) v += ps[b][i] * pw1[j * 64 + i];
        p1[b][j] = leaky(v);
    }
    __syncthreads();
    for (int idx = t; idx < 1024; idx += 256) {
        int b = idx >> 5, j = idx & 31;
        float v = pb2[j];
#pragma unroll 8
        for (int i = 0; i < 64; i++) v += p1[b][i] * pw2[j * 64 + i];
        p2[b][j] = leaky(v);
    }
    __syncthreads();
    if (t < 32) {
        float v = pb3[0];
#pragma unroll 8
        for (int i = 0; i < 32; i++) v += p2[t][i] * pw3[i];
        out[t] = v;
    }
}

// ----------------------------------------------------------------
extern "C" void kernel_launch(void* const* d_in, const int* in_sizes, int n_in,
                              void* d_out, int out_size, void* d_ws, size_t ws_size,
                              hipStream_t stream) {
    const float* x    = (const float*)d_in[0];
    const int*   eidx = (const int*)  d_in[1];
    const float* ea   = (const float*)d_in[2];
    const int*   bat  = (const int*)  d_in[3];
    const float* Win  = (const float*)d_in[4];
    const float* bin  = (const float*)d_in[5];
    const float* ew1  = (const float*)d_in[6];
    const float* eb1  = (const float*)d_in[7];
    const float* ew2  = (const float*)d_in[8];
    const float* eb2  = (const float*)d_in[9];
    const float* ew3  = (const float*)d_in[10];
    const float* eb3  = (const float*)d_in[11];
    const float* rw   = (const float*)d_in[12];
    const float* rb   = (const float*)d_in[13];
    const float* lg   = (const float*)d_in[14];
    const float* lb   = (const float*)d_in[15];
    const float* pw1  = (const float*)d_in[16];
    const float* pb1  = (const float*)d_in[17];
    const float* pw2  = (const float*)d_in[18];
    const float* pb2  = (const float*)d_in[19];
    const float* pw3  = (const float*)d_in[20];
    const float* pb3  = (const float*)d_in[21];
    float* out = (float*)d_out;

    float* ws     = (float*)d_ws;
    float* h      = ws;                          // 1048576
    float* agg    = ws + 1048576;                // 3 * 1048576
    float* deg    = ws + 4194304;                // 16384
    float* pooled = ws + 4210688;                // 2048
    unsigned int* e2h = (unsigned int*)(ws + 4212800);   // 2097152 u32
    f16* Bp       = (f16*)(ws + 4212800 + 2097152);      // 3 * 266240 f16

    const int* srcp = eidx;
    const int* dstp = eidx + N_EDGES;

    (void)hipMemsetAsync(agg, 0, (size_t)3164224 * sizeof(float), stream);

    k_init   <<<4352, 256, 0, stream>>>(x, Win, bin, dstp, h, deg);
    k_prep_bp<<<390, 256, 0, stream>>>(ew3, eb3, Bp);

    for (int l = 0; l < NLAYERS; l++) {
        float* agg_l = agg + (size_t)l * N_NODES * H;
        k_edge_mlp<<<N_EDGES / 128, 256, 0, stream>>>(ea, ew1 + l * 320, eb1 + l * 64,
                                                      ew2 + l * 4096, eb2 + l * 64,
                                                      (unsigned short*)e2h);
        k_msg     <<<N_EDGES / 256, 256, 0, stream>>>(h, e2h, Bp + (size_t)l * 266240,
                                                      srcp, dstp, agg_l);
        k_node    <<<N_NODES / 64, 256, 0, stream>>>(agg_l, deg, rw + l * 4096, rb + l * 64,
                                                     lg + l * 64, lb + l * 64, h,
                                                     bat, pooled, l == NLAYERS - 1 ? 1 : 0);
    }

    k_head<<<1, 256, 0, stream>>>(pooled, bat, pw1, pb1, pw2, pb2, pw3, pb3, out);
}

// Round 7
// 349.641 us; speedup vs baseline: 1.3010x; 1.3010x over previous
//
#include <hip/hip_runtime.h>
#include <hip/hip_bf16.h>

#define N_NODES 16384
#define N_EDGES 65536
#define NB      32
#define H       64
#define NLAYERS 3
#define NEG     0.1f
#define LN_EPS  1e-5f

typedef _Float16 f16;
typedef _Float16 f16x2 __attribute__((ext_vector_type(2)));
typedef _Float16 f16x8 __attribute__((ext_vector_type(8)));
typedef __fp16   hf16x2 __attribute__((ext_vector_type(2)));
typedef float    f32x16 __attribute__((ext_vector_type(16)));

union F16x8 { f16x8 v; f16x2 p[4]; int4 i4; int2 i2[2]; };
union F16x2U { f16x2 h2; hf16x2 raw; unsigned int u; };
union F16U   { f16 h; unsigned short u; };

__device__ __forceinline__ f16x2 pkrtz(float a, float b) {
    F16x2U t; t.raw = __builtin_amdgcn_cvt_pkrtz(a, b); return t.h2;
}
__device__ __forceinline__ float leaky(float v) { return v > 0.f ? v : NEG * v; }

// ---------------------------------------------------------------- init: inproj + degree (fused)
__global__ __launch_bounds__(256) void k_init(const float* __restrict__ x,
                                              const float* __restrict__ Win,
                                              const float* __restrict__ bin,
                                              const int* __restrict__ dst,
                                              float* __restrict__ h,
                                              float* __restrict__ deg) {
    int bid = blockIdx.x;
    if (bid < 4096) {
        int t = bid * 256 + threadIdx.x;
        int n = t >> 6, j = t & 63;
        const float* xr = x + n * 4;
        const float* wr = Win + j * 4;
        float v = bin[j] + xr[0] * wr[0] + xr[1] * wr[1] + xr[2] * wr[2] + xr[3] * wr[3];
        h[t] = leaky(v);
    } else {
        int e = (bid - 4096) * 256 + threadIdx.x;
        atomicAdd(&deg[dst[e]], 1.0f);
    }
}

// ---------------------------------------------------------------- Bp (3 layers): MFMA-fragment f16 B
// slot = i*8 + ks*2 + oq (i in [0,64]; i==64 = eb3 bias). layer stride 520 slots.
__global__ __launch_bounds__(256) void k_prep_bp(const float* __restrict__ ew3,
                                                 const float* __restrict__ eb3,
                                                 f16* __restrict__ Bp) {
    int tg    = blockIdx.x * 256 + threadIdx.x;
    int lane  = tg & 63;
    int gslot = tg >> 6;
    int l     = gslot / 520;
    int slot  = gslot - l * 520;
    const float* ew3l = ew3 + (size_t)l * 262144;
    const float* eb3l = eb3 + (size_t)l * 4096;
    int i   = slot >> 3;
    int rem = slot & 7;
    int ks  = rem >> 1;
    int oq  = rem & 1;
    int o   = oq * 32 + (lane & 31);
    int k0  = ks * 16 + (lane >> 5) * 8;
    float v[8];
    if (i < 64) {
        const float* s = ew3l + ((size_t)(i * 64 + o)) * 64 + k0;
        float4 a = ((const float4*)s)[0];
        float4 b = ((const float4*)s)[1];
        v[0] = a.x; v[1] = a.y; v[2] = a.z; v[3] = a.w;
        v[4] = b.x; v[5] = b.y; v[6] = b.z; v[7] = b.w;
    } else {
#pragma unroll
        for (int j = 0; j < 8; j++) v[j] = eb3l[(k0 + j) * 64 + o];
    }
    union { int4 i4; f16 a[8]; } out;
#pragma unroll
    for (int j = 0; j < 8; j++) out.a[j] = (f16)v[j];
    *(int4*)(Bp + (size_t)l * 266240 + (size_t)slot * 512 + lane * 8) = out.i4;
}

// ---------------------------------------------------------------- edge MLP (MFMA stage2), f16 output
__global__ __launch_bounds__(256) void k_edge_mlp(const float* __restrict__ ea,
                                                  const float* __restrict__ w1,
                                                  const float* __restrict__ b1,
                                                  const float* __restrict__ w2,
                                                  const float* __restrict__ b2,
                                                  unsigned short* __restrict__ e2h) {
    __shared__ float eas[128 * 8];
    __shared__ __align__(16) unsigned short e1L[128 * 72];
    int t = threadIdx.x;
    int eb = blockIdx.x * 128;

    for (int idx = t; idx < 640; idx += 256) {
        int r = idx / 5, d = idx - r * 5;
        eas[r * 8 + d] = ea[(size_t)eb * 5 + idx];
    }
    __syncthreads();

    {
        int kk = t & 63;
        int eg = t >> 6;
        float w1r[5];
#pragma unroll
        for (int d = 0; d < 5; d++) w1r[d] = w1[kk * 5 + d];
        float b1r = b1[kk];
        for (int g = 0; g < 32; g++) {
            int row = g * 4 + eg;
            float4 a4 = *(const float4*)(eas + row * 8);
            float a5 = eas[row * 8 + 4];
            float v = b1r + a4.x * w1r[0] + a4.y * w1r[1] + a4.z * w1r[2] + a4.w * w1r[3] + a5 * w1r[4];
            F16U z; z.h = (f16)leaky(v);
            e1L[row * 72 + kk] = z.u;
        }
    }
    __syncthreads();

    int lane = t & 63;
    int w    = t >> 6;
    int eq2  = w >> 1, oq = w & 1;
    int m    = lane & 31;
    int kp   = lane >> 5;

    F16x8 Bf[4];
#pragma unroll
    for (int ks = 0; ks < 4; ks++) {
        const float* s = w2 + (size_t)(oq * 32 + m) * 64 + ks * 16 + kp * 8;
        float4 a = ((const float4*)s)[0];
        float4 b = ((const float4*)s)[1];
        Bf[ks].p[0] = pkrtz(a.x, a.y);
        Bf[ks].p[1] = pkrtz(a.z, a.w);
        Bf[ks].p[2] = pkrtz(b.x, b.y);
        Bf[ks].p[3] = pkrtz(b.z, b.w);
    }
    float b2r = b2[oq * 32 + m];

    f32x16 C0 = {0,0,0,0,0,0,0,0,0,0,0,0,0,0,0,0};
    f32x16 C1 = {0,0,0,0,0,0,0,0,0,0,0,0,0,0,0,0};
#pragma unroll
    for (int ks = 0; ks < 4; ks++) {
        int koff = (ks * 16 + kp * 8);
        F16x8 A0, A1;
        A0.i4 = *(const int4*)(e1L + (size_t)(eq2 * 64 + m) * 72 + koff);
        A1.i4 = *(const int4*)(e1L + (size_t)(eq2 * 64 + 32 + m) * 72 + koff);
        C0 = __builtin_amdgcn_mfma_f32_32x32x16_f16(A0.v, Bf[ks].v, C0, 0, 0, 0);
        C1 = __builtin_amdgcn_mfma_f32_32x32x16_f16(A1.v, Bf[ks].v, C1, 0, 0, 0);
    }

    int o = oq * 32 + m;
#pragma unroll
    for (int reg = 0; reg < 16; reg++) {
        int r = (reg & 3) + 8 * (reg >> 2) + 4 * kp;
        F16U z; z.h = (f16)leaky(C0[reg] + b2r);
        e2h[(size_t)(eb + eq2 * 64 + r) * 64 + o] = z.u;
    }
#pragma unroll
    for (int reg = 0; reg < 16; reg++) {
        int r = (reg & 3) + 8 * (reg >> 2) + 4 * kp;
        F16U z; z.h = (f16)leaky(C1[reg] + b2r);
        e2h[(size_t)(eb + eq2 * 64 + 32 + r) * 64 + o] = z.u;
    }
}

// ---------------------------------------------------------------- fused bilinear MFMA GEMM + scatter
// block = 256 edges, 4 waves; wave (eh, oq): 4 edge-tiles (eh*128..+127) x 32 outputs.
// K-loop is barrier-free with a STATIC 2-buffer register pipeline (no runtime
// pointer selection — that demotes register arrays to scratch, round-6 lesson).
#define HS_STRIDE 76   // u16; 152 B rows -> 2-way LDS banks (free)

__device__ __forceinline__ void loadB8(const f16* __restrict__ Bp, int c, int oq, int lane, F16x8* dstB) {
    const f16* base = Bp + (((size_t)(c * 16 + oq)) << 9) + lane * 8;
#pragma unroll
    for (int di = 0; di < 2; di++)
#pragma unroll
        for (int ks = 0; ks < 4; ks++)
            dstB[di * 4 + ks].i4 = *(const int4*)(base + ((di * 8 + ks * 2) << 9));
}
__device__ __forceinline__ void loadB4(const f16* __restrict__ Bp, int oq, int lane, F16x8* dstB) {
    const f16* base = Bp + (((size_t)(512 + oq)) << 9) + lane * 8;
#pragma unroll
    for (int ks = 0; ks < 4; ks++)
        dstB[ks].i4 = *(const int4*)(base + ((ks * 2) << 9));
}

__device__ __forceinline__ void msg_chunk4(int c, const F16x8* __restrict__ B,
                                           const unsigned short* const* hp,
                                           const f16x2 (*e2p)[4][4], f32x16* C) {
    unsigned int rr[4];
#pragma unroll
    for (int tt = 0; tt < 4; tt++) rr[tt] = *(const unsigned int*)(hp[tt] + 2 * c);
#pragma unroll
    for (int di = 0; di < 2; di++) {
        unsigned int sel = di ? 0x03020302u : 0x01000100u;
        F16x2U hh[4];
#pragma unroll
        for (int tt = 0; tt < 4; tt++) hh[tt].u = __builtin_amdgcn_perm(rr[tt], rr[tt], sel);
#pragma unroll
        for (int ks = 0; ks < 4; ks++) {
#pragma unroll
            for (int tt = 0; tt < 4; tt++) {
                F16x8 A;
#pragma unroll
                for (int r = 0; r < 4; r++) A.p[r] = hh[tt].h2 * e2p[tt][ks][r];
                C[tt] = __builtin_amdgcn_mfma_f32_32x32x16_f16(A.v, B[di * 4 + ks].v, C[tt], 0, 0, 0);
            }
        }
    }
}

__global__ __launch_bounds__(256, 1) void k_msg(const float* __restrict__ h,
                                                const unsigned int* __restrict__ e2h,
                                                const f16* __restrict__ Bp,
                                                const int* __restrict__ src,
                                                const int* __restrict__ dst,
                                                float* __restrict__ agg) {
    __shared__ __align__(16) unsigned short hsL[256 * HS_STRIDE];  // 38.9 KB
    __shared__ int dstL[256];

    const int t    = threadIdx.x;
    const int lane = t & 63;
    const int w    = t >> 6;
    const int eh   = w >> 1, oq = w & 1;
    const int m    = lane & 31;
    const int kp   = lane >> 5;
    const int eb   = blockIdx.x * 256;

    // ---- stage h rows (gathered by src, fp32 -> f16): thread t owns row t
    {
        int nsrc = src[eb + t];
        const float4* hr = (const float4*)(h + (size_t)nsrc * 64);
        unsigned int* hrow = (unsigned int*)hsL + t * (HS_STRIDE / 2);
#pragma unroll
        for (int q = 0; q < 16; q++) {
            float4 v = hr[q];
            F16x2U p0, p1;
            p0.raw = __builtin_amdgcn_cvt_pkrtz(v.x, v.y);
            p1.raw = __builtin_amdgcn_cvt_pkrtz(v.z, v.w);
            hrow[q * 2 + 0] = p0.u;
            hrow[q * 2 + 1] = p1.u;
        }
        dstL[t] = dst[eb + t];
    }

    // ---- e2 rows (f16 pairs) for this wave's 4 edge-tiles: 64 VGPRs
    f16x2 e2p[4][4][4];
#pragma unroll
    for (int tt = 0; tt < 4; tt++) {
        const unsigned int* row = e2h + (size_t)(eb + (eh * 4 + tt) * 32 + m) * 32;
#pragma unroll
        for (int ks = 0; ks < 4; ks++) {
            int4 q = *(const int4*)(row + ks * 8 + kp * 4);
            F16x2U u0, u1, u2, u3;
            u0.u = q.x; u1.u = q.y; u2.u = q.z; u3.u = q.w;
            e2p[tt][ks][0] = u0.h2; e2p[tt][ks][1] = u1.h2;
            e2p[tt][ks][2] = u2.h2; e2p[tt][ks][3] = u3.h2;
        }
    }
    __syncthreads();

    f32x16 C[4];
#pragma unroll
    for (int tt = 0; tt < 4; tt++)
#pragma unroll
        for (int r = 0; r < 16; r++) C[tt][r] = 0.f;

    const unsigned short* hp[4];
#pragma unroll
    for (int tt = 0; tt < 4; tt++)
        hp[tt] = hsL + ((eh * 4 + tt) * 32 + m) * HS_STRIDE;

    // ---- STATIC double-buffered K-loop (refill each buffer right after use)
    F16x8 B0[8], B1[8];
    loadB8(Bp, 0, oq, lane, B0);
    loadB8(Bp, 1, oq, lane, B1);
    for (int it = 0; it < 15; it++) {
        int c = it * 2;
        msg_chunk4(c,     B0, hp, e2p, C);  loadB8(Bp, c + 2, oq, lane, B0);
        msg_chunk4(c + 1, B1, hp, e2p, C);  loadB8(Bp, c + 3, oq, lane, B1);
    }
    msg_chunk4(30, B0, hp, e2p, C);
    loadB4(Bp, oq, lane, B0);               // bias frags into B0[0..3]
    msg_chunk4(31, B1, hp, e2p, C);

    // ---- bias chunk: A = h itself (k plays the i role), B = eb3 frags
#pragma unroll
    for (int ks = 0; ks < 4; ks++) {
        int koff = (ks * 16 + kp * 8) * 2;
#pragma unroll
        for (int tt = 0; tt < 4; tt++) {
            const char* rp = (const char*)hsL + (size_t)((eh * 4 + tt) * 32 + m) * (HS_STRIDE * 2) + koff;
            F16x8 A;
            A.i2[0] = *(const int2*)(rp); A.i2[1] = *(const int2*)(rp + 8);
            C[tt] = __builtin_amdgcn_mfma_f32_32x32x16_f16(A.v, B0[ks].v, C[tt], 0, 0, 0);
        }
    }

    // ---- scatter epilogue: C/D layout col=m, row=(reg&3)+8*(reg>>2)+4*kp
    int o = oq * 32 + m;
#pragma unroll
    for (int tt = 0; tt < 4; tt++) {
#pragma unroll
        for (int reg = 0; reg < 16; reg++) {
            int r = (reg & 3) + 8 * (reg >> 2) + 4 * kp;
            atomicAdd(&agg[(size_t)dstL[(eh * 4 + tt) * 32 + r] * 64 + o], C[tt][reg]);
        }
    }
}

// ---------------------------------------------------------------- node update: MFMA root GEMM + LN + residual (+pool on last)
__global__ __launch_bounds__(256) void k_node(const float* __restrict__ agg,
                                              const float* __restrict__ deg,
                                              const float* __restrict__ rw,
                                              const float* __restrict__ rb,
                                              const float* __restrict__ lg,
                                              const float* __restrict__ lb,
                                              float* __restrict__ h,
                                              const int* __restrict__ batch,
                                              float* __restrict__ pooled,
                                              int last) {
    __shared__ __align__(16) unsigned short hA[64 * 72];
    __shared__ float outL[64][68];
    int t = threadIdx.x;
    int nb = blockIdx.x * 64;
    int lane = t & 63, w = t >> 6;
    int nq = w >> 1, oq = w & 1;
    int m = lane & 31, kp = lane >> 5;

    {
        int r = t >> 2, c0 = (t & 3) * 16;
        const float4* hr = (const float4*)(h + (size_t)(nb + r) * 64 + c0);
        unsigned int* drow = (unsigned int*)hA + r * 36 + c0 / 2;
#pragma unroll
        for (int q = 0; q < 4; q++) {
            float4 v = hr[q];
            F16x2U p0, p1;
            p0.raw = __builtin_amdgcn_cvt_pkrtz(v.x, v.y);
            p1.raw = __builtin_amdgcn_cvt_pkrtz(v.z, v.w);
            drow[q * 2] = p0.u; drow[q * 2 + 1] = p1.u;
        }
    }
    F16x8 Bf[4];
#pragma unroll
    for (int ks = 0; ks < 4; ks++) {
        const float* s = rw + (size_t)(oq * 32 + m) * 64 + ks * 16 + kp * 8;
        float4 a = ((const float4*)s)[0];
        float4 b = ((const float4*)s)[1];
        Bf[ks].p[0] = pkrtz(a.x, a.y);
        Bf[ks].p[1] = pkrtz(a.z, a.w);
        Bf[ks].p[2] = pkrtz(b.x, b.y);
        Bf[ks].p[3] = pkrtz(b.z, b.w);
    }
    __syncthreads();

    f32x16 C = {0,0,0,0,0,0,0,0,0,0,0,0,0,0,0,0};
#pragma unroll
    for (int ks = 0; ks < 4; ks++) {
        F16x8 A;
        A.i4 = *(const int4*)(hA + (size_t)(nq * 32 + m) * 72 + ks * 16 + kp * 8);
        C = __builtin_amdgcn_mfma_f32_32x32x16_f16(A.v, Bf[ks].v, C, 0, 0, 0);
    }

    int o = oq * 32 + m;
#pragma unroll
    for (int reg = 0; reg < 16; reg++) {
        int r = (reg & 3) + 8 * (reg >> 2) + 4 * kp;
        int n = nq * 32 + r;
        outL[n][o] = C[reg] + rb[o] + agg[(size_t)(nb + n) * 64 + o] / fmaxf(deg[nb + n], 1.0f);
    }
    __syncthreads();

    float gj = lg[lane], bj = lb[lane];
    float accp = 0.f;
    int cur = batch[nb + w * 16];
    for (int q = 0; q < 16; q++) {
        int n = w * 16 + q;
        float v = outL[n][lane];
        float mu = v;
#pragma unroll
        for (int msk = 32; msk > 0; msk >>= 1) mu += __shfl_xor(mu, msk);
        mu *= (1.f / 64.f);
        float d = v - mu;
        float var = d * d;
#pragma unroll
        for (int msk = 32; msk > 0; msk >>= 1) var += __shfl_xor(var, msk);
        var *= (1.f / 64.f);
        float ov = d * rsqrtf(var + LN_EPS) * gj + bj;
        float hn = leaky(ov) + h[(size_t)(nb + n) * 64 + lane];
        h[(size_t)(nb + n) * 64 + lane] = hn;
        if (last) {
            int b = batch[nb + n];
            if (b != cur) { atomicAdd(&pooled[cur * 64 + lane], accp); accp = 0.f; cur = b; }
            accp += hn;
        }
    }
    if (last) atomicAdd(&pooled[cur * 64 + lane], accp);
}

// ---------------------------------------------------------------- prediction head (1 block; computes cnt from sorted batch)
__global__ __launch_bounds__(256) void k_head(const float* __restrict__ pooled,
                                              const int* __restrict__ batch,
                                              const float* __restrict__ pw1, const float* __restrict__ pb1,
                                              const float* __restrict__ pw2, const float* __restrict__ pb2,
                                              const float* __restrict__ pw3, const float* __restrict__ pb3,
                                              float* __restrict__ out) {
    __shared__ float cntL[32];
    __shared__ float ps[32][64];
    __shared__ float p1[32][64];
    __shared__ float p2[32][32];
    int t = threadIdx.x;
    if (t < 32) cntL[t] = 0.f;
    __syncthreads();
    {
        const int4* bp4 = (const int4*)(batch + t * 64);
        int cur = batch[t * 64];
        float c = 0.f;
        for (int q = 0; q < 16; q++) {
            int4 b4 = bp4[q];
            int bs[4] = { b4.x, b4.y, b4.z, b4.w };
#pragma unroll
            for (int e = 0; e < 4; e++) {
                if (bs[e] != cur) { atomicAdd(&cntL[cur], c); cur = bs[e]; c = 0.f; }
                c += 1.f;
            }
        }
        atomicAdd(&cntL[cur], c);
    }
    __syncthreads();
    for (int idx = t; idx < 2048; idx += 256) {
        int b = idx >> 6, j = idx & 63;
        ps[b][j] = pooled[idx] / fmaxf(cntL[b], 1.0f);
    }
    __syncthreads();
    for (int idx = t; idx < 2048; idx += 256) {
        int b = idx >> 6, j = idx & 63;
        float v = pb1[j];
#pragma unroll 8
        for (int i = 0; i < 64; i++) v += ps[b][i] * pw1[j * 64 + i];
        p1[b][j] = leaky(v);
    }
    __syncthreads();
    for (int idx = t; idx < 1024; idx += 256) {
        int b = idx >> 5, j = idx & 31;
        float v = pb2[j];
#pragma unroll 8
        for (int i = 0; i < 64; i++) v += p1[b][i] * pw2[j * 64 + i];
        p2[b][j] = leaky(v);
    }
    __syncthreads();
    if (t < 32) {
        float v = pb3[0];
#pragma unroll 8
        for (int i = 0; i < 32; i++) v += p2[t][i] * pw3[i];
        out[t] = v;
    }
}

// ----------------------------------------------------------------
extern "C" void kernel_launch(void* const* d_in, const int* in_sizes, int n_in,
                              void* d_out, int out_size, void* d_ws, size_t ws_size,
                              hipStream_t stream) {
    const float* x    = (const float*)d_in[0];
    const int*   eidx = (const int*)  d_in[1];
    const float* ea   = (const float*)d_in[2];
    const int*   bat  = (const int*)  d_in[3];
    const float* Win  = (const float*)d_in[4];
    const float* bin  = (const float*)d_in[5];
    const float* ew1  = (const float*)d_in[6];
    const float* eb1  = (const float*)d_in[7];
    const float* ew2  = (const float*)d_in[8];
    const float* eb2  = (const float*)d_in[9];
    const float* ew3  = (const float*)d_in[10];
    const float* eb3  = (const float*)d_in[11];
    const float* rw   = (const float*)d_in[12];
    const float* rb   = (const float*)d_in[13];
    const float* lg   = (const float*)d_in[14];
    const float* lb   = (const float*)d_in[15];
    const float* pw1  = (const float*)d_in[16];
    const float* pb1  = (const float*)d_in[17];
    const float* pw2  = (const float*)d_in[18];
    const float* pb2  = (const float*)d_in[19];
    const float* pw3  = (const float*)d_in[20];
    const float* pb3  = (const float*)d_in[21];
    float* out = (float*)d_out;

    float* ws     = (float*)d_ws;
    float* h      = ws;                          // 1048576
    float* agg    = ws + 1048576;                // 3 * 1048576
    float* deg    = ws + 4194304;                // 16384
    float* pooled = ws + 4210688;                // 2048
    unsigned int* e2h = (unsigned int*)(ws + 4212800);   // 2097152 u32
    f16* Bp       = (f16*)(ws + 4212800 + 2097152);      // 3 * 266240 f16

    const int* srcp = eidx;
    const int* dstp = eidx + N_EDGES;

    (void)hipMemsetAsync(agg, 0, (size_t)3164224 * sizeof(float), stream);

    k_init   <<<4352, 256, 0, stream>>>(x, Win, bin, dstp, h, deg);
    k_prep_bp<<<390, 256, 0, stream>>>(ew3, eb3, Bp);

    for (int l = 0; l < NLAYERS; l++) {
        float* agg_l = agg + (size_t)l * N_NODES * H;
        k_edge_mlp<<<N_EDGES / 128, 256, 0, stream>>>(ea, ew1 + l * 320, eb1 + l * 64,
                                                      ew2 + l * 4096, eb2 + l * 64,
                                                      (unsigned short*)e2h);
        k_msg     <<<N_EDGES / 256, 256, 0, stream>>>(h, e2h, Bp + (size_t)l * 266240,
                                                      srcp, dstp, agg_l);
        k_node    <<<N_NODES / 64, 256, 0, stream>>>(agg_l, deg, rw + l * 4096, rb + l * 64,
                                                     lg + l * 64, lb + l * 64, h,
                                                     bat, pooled, l == NLAYERS - 1 ? 1 : 0);
    }

    k_head<<<1, 256, 0, stream>>>(pooled, bat, pw1, pb1, pw2, pb2, pw3, pb3, out);
}

// Round 8
// 340.141 us; speedup vs baseline: 1.3373x; 1.0279x over previous
//
#include <hip/hip_runtime.h>
#include <hip/hip_bf16.h>

#define N_NODES 16384
#define N_EDGES 65536
#define NB      32
#define H       64
#define NLAYERS 3
#define NEG     0.1f
#define LN_EPS  1e-5f

typedef _Float16 f16;
typedef _Float16 f16x2 __attribute__((ext_vector_type(2)));
typedef _Float16 f16x8 __attribute__((ext_vector_type(8)));
typedef __fp16   hf16x2 __attribute__((ext_vector_type(2)));
typedef float    f32x16 __attribute__((ext_vector_type(16)));

union F16x8 { f16x8 v; f16x2 p[4]; int4 i4; int2 i2[2]; };
union F16x2U { f16x2 h2; hf16x2 raw; unsigned int u; };
union F16U   { f16 h; unsigned short u; };

__device__ __forceinline__ f16x2 pkrtz(float a, float b) {
    F16x2U t; t.raw = __builtin_amdgcn_cvt_pkrtz(a, b); return t.h2;
}
__device__ __forceinline__ float leaky(float v) { return v > 0.f ? v : NEG * v; }

// ---------------------------------------------------------------- init: inproj + degree (fused)
__global__ __launch_bounds__(256) void k_init(const float* __restrict__ x,
                                              const float* __restrict__ Win,
                                              const float* __restrict__ bin,
                                              const int* __restrict__ dst,
                                              float* __restrict__ h,
                                              float* __restrict__ deg) {
    int bid = blockIdx.x;
    if (bid < 4096) {
        int t = bid * 256 + threadIdx.x;
        int n = t >> 6, j = t & 63;
        const float* xr = x + n * 4;
        const float* wr = Win + j * 4;
        float v = bin[j] + xr[0] * wr[0] + xr[1] * wr[1] + xr[2] * wr[2] + xr[3] * wr[3];
        h[t] = leaky(v);
    } else {
        int e = (bid - 4096) * 256 + threadIdx.x;
        atomicAdd(&deg[dst[e]], 1.0f);
    }
}

// ---------------------------------------------------------------- Bp (3 layers): MFMA-fragment f16 B
// slot = i*8 + ks*2 + oq (i in [0,64]; i==64 = eb3 bias). layer stride 520 slots.
__global__ __launch_bounds__(256) void k_prep_bp(const float* __restrict__ ew3,
                                                 const float* __restrict__ eb3,
                                                 f16* __restrict__ Bp) {
    int tg    = blockIdx.x * 256 + threadIdx.x;
    int lane  = tg & 63;
    int gslot = tg >> 6;
    int l     = gslot / 520;
    int slot  = gslot - l * 520;
    const float* ew3l = ew3 + (size_t)l * 262144;
    const float* eb3l = eb3 + (size_t)l * 4096;
    int i   = slot >> 3;
    int rem = slot & 7;
    int ks  = rem >> 1;
    int oq  = rem & 1;
    int o   = oq * 32 + (lane & 31);
    int k0  = ks * 16 + (lane >> 5) * 8;
    float v[8];
    if (i < 64) {
        const float* s = ew3l + ((size_t)(i * 64 + o)) * 64 + k0;
        float4 a = ((const float4*)s)[0];
        float4 b = ((const float4*)s)[1];
        v[0] = a.x; v[1] = a.y; v[2] = a.z; v[3] = a.w;
        v[4] = b.x; v[5] = b.y; v[6] = b.z; v[7] = b.w;
    } else {
#pragma unroll
        for (int j = 0; j < 8; j++) v[j] = eb3l[(k0 + j) * 64 + o];
    }
    union { int4 i4; f16 a[8]; } out;
#pragma unroll
    for (int j = 0; j < 8; j++) out.a[j] = (f16)v[j];
    *(int4*)(Bp + (size_t)l * 266240 + (size_t)slot * 512 + lane * 8) = out.i4;
}

// ---------------------------------------------------------------- edge MLP (MFMA stage2), f16 output
__global__ __launch_bounds__(256) void k_edge_mlp(const float* __restrict__ ea,
                                                  const float* __restrict__ w1,
                                                  const float* __restrict__ b1,
                                                  const float* __restrict__ w2,
                                                  const float* __restrict__ b2,
                                                  unsigned short* __restrict__ e2h) {
    __shared__ float eas[128 * 8];
    __shared__ __align__(16) unsigned short e1L[128 * 72];
    int t = threadIdx.x;
    int eb = blockIdx.x * 128;

    for (int idx = t; idx < 640; idx += 256) {
        int r = idx / 5, d = idx - r * 5;
        eas[r * 8 + d] = ea[(size_t)eb * 5 + idx];
    }
    __syncthreads();

    {
        int kk = t & 63;
        int eg = t >> 6;
        float w1r[5];
#pragma unroll
        for (int d = 0; d < 5; d++) w1r[d] = w1[kk * 5 + d];
        float b1r = b1[kk];
        for (int g = 0; g < 32; g++) {
            int row = g * 4 + eg;
            float4 a4 = *(const float4*)(eas + row * 8);
            float a5 = eas[row * 8 + 4];
            float v = b1r + a4.x * w1r[0] + a4.y * w1r[1] + a4.z * w1r[2] + a4.w * w1r[3] + a5 * w1r[4];
            F16U z; z.h = (f16)leaky(v);
            e1L[row * 72 + kk] = z.u;
        }
    }
    __syncthreads();

    int lane = t & 63;
    int w    = t >> 6;
    int eq2  = w >> 1, oq = w & 1;
    int m    = lane & 31;
    int kp   = lane >> 5;

    F16x8 Bf[4];
#pragma unroll
    for (int ks = 0; ks < 4; ks++) {
        const float* s = w2 + (size_t)(oq * 32 + m) * 64 + ks * 16 + kp * 8;
        float4 a = ((const float4*)s)[0];
        float4 b = ((const float4*)s)[1];
        Bf[ks].p[0] = pkrtz(a.x, a.y);
        Bf[ks].p[1] = pkrtz(a.z, a.w);
        Bf[ks].p[2] = pkrtz(b.x, b.y);
        Bf[ks].p[3] = pkrtz(b.z, b.w);
    }
    float b2r = b2[oq * 32 + m];

    f32x16 C0 = {0,0,0,0,0,0,0,0,0,0,0,0,0,0,0,0};
    f32x16 C1 = {0,0,0,0,0,0,0,0,0,0,0,0,0,0,0,0};
#pragma unroll
    for (int ks = 0; ks < 4; ks++) {
        int koff = (ks * 16 + kp * 8);
        F16x8 A0, A1;
        A0.i4 = *(const int4*)(e1L + (size_t)(eq2 * 64 + m) * 72 + koff);
        A1.i4 = *(const int4*)(e1L + (size_t)(eq2 * 64 + 32 + m) * 72 + koff);
        C0 = __builtin_amdgcn_mfma_f32_32x32x16_f16(A0.v, Bf[ks].v, C0, 0, 0, 0);
        C1 = __builtin_amdgcn_mfma_f32_32x32x16_f16(A1.v, Bf[ks].v, C1, 0, 0, 0);
    }

    int o = oq * 32 + m;
#pragma unroll
    for (int reg = 0; reg < 16; reg++) {
        int r = (reg & 3) + 8 * (reg >> 2) + 4 * kp;
        F16U z; z.h = (f16)leaky(C0[reg] + b2r);
        e2h[(size_t)(eb + eq2 * 64 + r) * 64 + o] = z.u;
    }
#pragma unroll
    for (int reg = 0; reg < 16; reg++) {
        int r = (reg & 3) + 8 * (reg >> 2) + 4 * kp;
        F16U z; z.h = (f16)leaky(C1[reg] + b2r);
        e2h[(size_t)(eb + eq2 * 64 + 32 + r) * 64 + o] = z.u;
    }
}

// ---------------------------------------------------------------- fused bilinear MFMA GEMM + scatter
// block = 128 edges, 4 waves (eh, oq); wave = 2 edge-tiles x 32 outputs.
// FOUR accumulator chains per wave (CC[di*2+tt], i-parity split) -> 128-cyc
// chain spacing covers MFMA dependent latency. grid 512 -> 2 blocks/CU ->
// 2 waves/SIMD so MFMA+VALU pipes co-schedule across waves (m114).
// Static register dbuf (NO runtime pointer selection - round-6 spill lesson).
#define HS_STRIDE 76   // u16; 152 B rows -> 2-way LDS banks (free)

__device__ __forceinline__ void loadB8(const f16* __restrict__ Bp, int c, int oq, int lane, F16x8* dstB) {
    const f16* base = Bp + (((size_t)(c * 16 + oq)) << 9) + lane * 8;
#pragma unroll
    for (int di = 0; di < 2; di++)
#pragma unroll
        for (int ks = 0; ks < 4; ks++)
            dstB[di * 4 + ks].i4 = *(const int4*)(base + ((di * 8 + ks * 2) << 9));
}
__device__ __forceinline__ void loadB4(const f16* __restrict__ Bp, int oq, int lane, F16x8* dstB) {
    const f16* base = Bp + (((size_t)(512 + oq)) << 9) + lane * 8;
#pragma unroll
    for (int ks = 0; ks < 4; ks++)
        dstB[ks].i4 = *(const int4*)(base + ((ks * 2) << 9));
}

// one chunk (2 i-slots): 16 MFMA across 4 chains CC[di*2+tt]
__device__ __forceinline__ void msg_chunk2(int c, const F16x8* __restrict__ B,
                                           const unsigned short* hp0,
                                           const unsigned short* hp1,
                                           const f16x2 (*e2p)[4][4], f32x16* CC) {
    unsigned int rr0 = *(const unsigned int*)(hp0 + 2 * c);   // h[2c],h[2c+1] tile0
    unsigned int rr1 = *(const unsigned int*)(hp1 + 2 * c);   // tile1
    F16x2U h00, h01, h10, h11;
    h00.u = __builtin_amdgcn_perm(rr0, rr0, 0x01000100u);     // di=0, tile0
    h10.u = __builtin_amdgcn_perm(rr0, rr0, 0x03020302u);     // di=1, tile0
    h01.u = __builtin_amdgcn_perm(rr1, rr1, 0x01000100u);     // di=0, tile1
    h11.u = __builtin_amdgcn_perm(rr1, rr1, 0x03020302u);     // di=1, tile1
#pragma unroll
    for (int ks = 0; ks < 4; ks++) {
        F16x8 A00, A01, A10, A11;
#pragma unroll
        for (int r = 0; r < 4; r++) {
            A00.p[r] = h00.h2 * e2p[0][ks][r];
            A01.p[r] = h01.h2 * e2p[1][ks][r];
            A10.p[r] = h10.h2 * e2p[0][ks][r];
            A11.p[r] = h11.h2 * e2p[1][ks][r];
        }
        // chain order: 0,1,2,3 -> spacing 4 MFMA = 128 cyc per chain
        CC[0] = __builtin_amdgcn_mfma_f32_32x32x16_f16(A00.v, B[0 * 4 + ks].v, CC[0], 0, 0, 0);
        CC[1] = __builtin_amdgcn_mfma_f32_32x32x16_f16(A01.v, B[0 * 4 + ks].v, CC[1], 0, 0, 0);
        CC[2] = __builtin_amdgcn_mfma_f32_32x32x16_f16(A10.v, B[1 * 4 + ks].v, CC[2], 0, 0, 0);
        CC[3] = __builtin_amdgcn_mfma_f32_32x32x16_f16(A11.v, B[1 * 4 + ks].v, CC[3], 0, 0, 0);
    }
}

__global__ __launch_bounds__(256, 2) void k_msg(const float* __restrict__ h,
                                                const unsigned int* __restrict__ e2h,
                                                const f16* __restrict__ Bp,
                                                const int* __restrict__ src,
                                                const int* __restrict__ dst,
                                                float* __restrict__ agg) {
    __shared__ __align__(16) unsigned short hsL[128 * HS_STRIDE];  // 19.5 KB
    __shared__ int dstL[128];

    const int t    = threadIdx.x;
    const int lane = t & 63;
    const int w    = t >> 6;
    const int eh   = w >> 1, oq = w & 1;   // wave: tiles eh*2, eh*2+1; outputs oq*32..+31
    const int m    = lane & 31;
    const int kp   = lane >> 5;
    const int eb   = blockIdx.x * 128;

    // ---- stage h rows (gathered by src, fp32 -> f16): 2 threads per row
    {
        int e    = t >> 1;
        int half = t & 1;
        int nsrc = src[eb + e];
        const float4* hr = (const float4*)(h + (size_t)nsrc * 64 + half * 32);
        unsigned int* hrow = (unsigned int*)hsL + e * (HS_STRIDE / 2) + half * 16;
#pragma unroll
        for (int q = 0; q < 8; q++) {
            float4 v = hr[q];
            F16x2U p0, p1;
            p0.raw = __builtin_amdgcn_cvt_pkrtz(v.x, v.y);
            p1.raw = __builtin_amdgcn_cvt_pkrtz(v.z, v.w);
            hrow[q * 2 + 0] = p0.u;
            hrow[q * 2 + 1] = p1.u;
        }
        if (t < 128) dstL[t] = dst[eb + t];
    }

    // ---- e2 rows (f16 pairs) for this wave's 2 edge-tiles: 32 VGPRs
    f16x2 e2p[2][4][4];
#pragma unroll
    for (int tt = 0; tt < 2; tt++) {
        const unsigned int* row = e2h + (size_t)(eb + (eh * 2 + tt) * 32 + m) * 32;
#pragma unroll
        for (int ks = 0; ks < 4; ks++) {
            int4 q = *(const int4*)(row + ks * 8 + kp * 4);
            F16x2U u0, u1, u2, u3;
            u0.u = q.x; u1.u = q.y; u2.u = q.z; u3.u = q.w;
            e2p[tt][ks][0] = u0.h2; e2p[tt][ks][1] = u1.h2;
            e2p[tt][ks][2] = u2.h2; e2p[tt][ks][3] = u3.h2;
        }
    }
    __syncthreads();

    f32x16 CC[4];
#pragma unroll
    for (int q = 0; q < 4; q++)
#pragma unroll
        for (int r = 0; r < 16; r++) CC[q][r] = 0.f;

    const unsigned short* hp0 = hsL + ((eh * 2 + 0) * 32 + m) * HS_STRIDE;
    const unsigned short* hp1 = hsL + ((eh * 2 + 1) * 32 + m) * HS_STRIDE;

    // ---- STATIC double-buffered barrier-free K-loop
    F16x8 B0[8], B1[8];
    loadB8(Bp, 0, oq, lane, B0);
    loadB8(Bp, 1, oq, lane, B1);
    for (int it = 0; it < 15; it++) {
        int c = it * 2;
        msg_chunk2(c,     B0, hp0, hp1, e2p, CC);  loadB8(Bp, c + 2, oq, lane, B0);
        msg_chunk2(c + 1, B1, hp0, hp1, e2p, CC);  loadB8(Bp, c + 3, oq, lane, B1);
    }
    msg_chunk2(30, B0, hp0, hp1, e2p, CC);
    loadB4(Bp, oq, lane, B0);               // bias frags into B0[0..3]
    msg_chunk2(31, B1, hp0, hp1, e2p, CC);

    // ---- bias chunk: A = h itself (k plays the i role), B = eb3 frags
#pragma unroll
    for (int ks = 0; ks < 4; ks++) {
        int koff = (ks * 16 + kp * 8) * 2;
        const char* r0p = (const char*)hsL + (size_t)((eh * 2 + 0) * 32 + m) * (HS_STRIDE * 2) + koff;
        const char* r1p = (const char*)hsL + (size_t)((eh * 2 + 1) * 32 + m) * (HS_STRIDE * 2) + koff;
        F16x8 A0, A1;
        A0.i2[0] = *(const int2*)(r0p); A0.i2[1] = *(const int2*)(r0p + 8);
        A1.i2[0] = *(const int2*)(r1p); A1.i2[1] = *(const int2*)(r1p + 8);
        CC[0] = __builtin_amdgcn_mfma_f32_32x32x16_f16(A0.v, B0[ks].v, CC[0], 0, 0, 0);
        CC[1] = __builtin_amdgcn_mfma_f32_32x32x16_f16(A1.v, B0[ks].v, CC[1], 0, 0, 0);
    }

    // ---- merge i-parity chains, scatter
    int o = oq * 32 + m;
#pragma unroll
    for (int reg = 0; reg < 16; reg++) {
        int r = (reg & 3) + 8 * (reg >> 2) + 4 * kp;
        atomicAdd(&agg[(size_t)dstL[(eh * 2 + 0) * 32 + r] * 64 + o], CC[0][reg] + CC[2][reg]);
    }
#pragma unroll
    for (int reg = 0; reg < 16; reg++) {
        int r = (reg & 3) + 8 * (reg >> 2) + 4 * kp;
        atomicAdd(&agg[(size_t)dstL[(eh * 2 + 1) * 32 + r] * 64 + o], CC[1][reg] + CC[3][reg]);
    }
}

// ---------------------------------------------------------------- node update: MFMA root GEMM + LN + residual (+pool on last)
__global__ __launch_bounds__(256) void k_node(const float* __restrict__ agg,
                                              const float* __restrict__ deg,
                                              const float* __restrict__ rw,
                                              const float* __restrict__ rb,
                                              const float* __restrict__ lg,
                                              const float* __restrict__ lb,
                                              float* __restrict__ h,
                                              const int* __restrict__ batch,
                                              float* __restrict__ pooled,
                                              int last) {
    __shared__ __align__(16) unsigned short hA[64 * 72];
    __shared__ float outL[64][68];
    int t = threadIdx.x;
    int nb = blockIdx.x * 64;
    int lane = t & 63, w = t >> 6;
    int nq = w >> 1, oq = w & 1;
    int m = lane & 31, kp = lane >> 5;

    {
        int r = t >> 2, c0 = (t & 3) * 16;
        const float4* hr = (const float4*)(h + (size_t)(nb + r) * 64 + c0);
        unsigned int* drow = (unsigned int*)hA + r * 36 + c0 / 2;
#pragma unroll
        for (int q = 0; q < 4; q++) {
            float4 v = hr[q];
            F16x2U p0, p1;
            p0.raw = __builtin_amdgcn_cvt_pkrtz(v.x, v.y);
            p1.raw = __builtin_amdgcn_cvt_pkrtz(v.z, v.w);
            drow[q * 2] = p0.u; drow[q * 2 + 1] = p1.u;
        }
    }
    F16x8 Bf[4];
#pragma unroll
    for (int ks = 0; ks < 4; ks++) {
        const float* s = rw + (size_t)(oq * 32 + m) * 64 + ks * 16 + kp * 8;
        float4 a = ((const float4*)s)[0];
        float4 b = ((const float4*)s)[1];
        Bf[ks].p[0] = pkrtz(a.x, a.y);
        Bf[ks].p[1] = pkrtz(a.z, a.w);
        Bf[ks].p[2] = pkrtz(b.x, b.y);
        Bf[ks].p[3] = pkrtz(b.z, b.w);
    }
    __syncthreads();

    f32x16 C = {0,0,0,0,0,0,0,0,0,0,0,0,0,0,0,0};
#pragma unroll
    for (int ks = 0; ks < 4; ks++) {
        F16x8 A;
        A.i4 = *(const int4*)(hA + (size_t)(nq * 32 + m) * 72 + ks * 16 + kp * 8);
        C = __builtin_amdgcn_mfma_f32_32x32x16_f16(A.v, Bf[ks].v, C, 0, 0, 0);
    }

    int o = oq * 32 + m;
#pragma unroll
    for (int reg = 0; reg < 16; reg++) {
        int r = (reg & 3) + 8 * (reg >> 2) + 4 * kp;
        int n = nq * 32 + r;
        outL[n][o] = C[reg] + rb[o] + agg[(size_t)(nb + n) * 64 + o] / fmaxf(deg[nb + n], 1.0f);
    }
    __syncthreads();

    float gj = lg[lane], bj = lb[lane];
    float accp = 0.f;
    int cur = batch[nb + w * 16];
    for (int q = 0; q < 16; q++) {
        int n = w * 16 + q;
        float v = outL[n][lane];
        float mu = v;
#pragma unroll
        for (int msk = 32; msk > 0; msk >>= 1) mu += __shfl_xor(mu, msk);
        mu *= (1.f / 64.f);
        float d = v - mu;
        float var = d * d;
#pragma unroll
        for (int msk = 32; msk > 0; msk >>= 1) var += __shfl_xor(var, msk);
        var *= (1.f / 64.f);
        float ov = d * rsqrtf(var + LN_EPS) * gj + bj;
        float hn = leaky(ov) + h[(size_t)(nb + n) * 64 + lane];
        h[(size_t)(nb + n) * 64 + lane] = hn;
        if (last) {
            int b = batch[nb + n];
            if (b != cur) { atomicAdd(&pooled[cur * 64 + lane], accp); accp = 0.f; cur = b; }
            accp += hn;
        }
    }
    if (last) atomicAdd(&pooled[cur * 64 + lane], accp);
}

// ---------------------------------------------------------------- prediction head (1 block; computes cnt from sorted batch)
__global__ __launch_bounds__(256) void k_head(const float* __restrict__ pooled,
                                              const int* __restrict__ batch,
                                              const float* __restrict__ pw1, const float* __restrict__ pb1,
                                              const float* __restrict__ pw2, const float* __restrict__ pb2,
                                              const float* __restrict__ pw3, const float* __restrict__ pb3,
                                              float* __restrict__ out) {
    __shared__ float cntL[32];
    __shared__ float ps[32][64];
    __shared__ float p1[32][64];
    __shared__ float p2[32][32];
    int t = threadIdx.x;
    if (t < 32) cntL[t] = 0.f;
    __syncthreads();
    {
        const int4* bp4 = (const int4*)(batch + t * 64);
        int cur = batch[t * 64];
        float c = 0.f;
        for (int q = 0; q < 16; q++) {
            int4 b4 = bp4[q];
            int bs[4] = { b4.x, b4.y, b4.z, b4.w };
#pragma unroll
            for (int e = 0; e < 4; e++) {
                if (bs[e] != cur) { atomicAdd(&cntL[cur], c); cur = bs[e]; c = 0.f; }
                c += 1.f;
            }
        }
        atomicAdd(&cntL[cur], c);
    }
    __syncthreads();
    for (int idx = t; idx < 2048; idx += 256) {
        int b = idx >> 6, j = idx & 63;
        ps[b][j] = pooled[idx] / fmaxf(cntL[b], 1.0f);
    }
    __syncthreads();
    for (int idx = t; idx < 2048; idx += 256) {
        int b = idx >> 6, j = idx & 63;
        float v = pb1[j];
#pragma unroll 8
        for (int i = 0; i < 64; i++) v += ps[b][i] * pw1[j * 64 + i];
        p1[b][j] = leaky(v);
    }
    __syncthreads();
    for (int idx = t; idx < 1024; idx += 256) {
        int b = idx >> 5, j = idx & 31;
        float v = pb2[j];
#pragma unroll 8
        for (int i = 0; i < 64; i++) v += p1[b][i] * pw2[j * 64 + i];
        p2[b][j] = leaky(v);
    }
    __syncthreads();
    if (t < 32) {
        float v = pb3[0];
#pragma unroll 8
        for (int i = 0; i < 32; i++) v += p2[t][i] * pw3[i];
        out[t] = v;
    }
}

// ----------------------------------------------------------------
extern "C" void kernel_launch(void* const* d_in, const int* in_sizes, int n_in,
                              void* d_out, int out_size, void* d_ws, size_t ws_size,
                              hipStream_t stream) {
    const float* x    = (const float*)d_in[0];
    const int*   eidx = (const int*)  d_in[1];
    const float* ea   = (const float*)d_in[2];
    const int*   bat  = (const int*)  d_in[3];
    const float* Win  = (const float*)d_in[4];
    const float* bin  = (const float*)d_in[5];
    const float* ew1  = (const float*)d_in[6];
    const float* eb1  = (const float*)d_in[7];
    const float* ew2  = (const float*)d_in[8];
    const float* eb2  = (const float*)d_in[9];
    const float* ew3  = (const float*)d_in[10];
    const float* eb3  = (const float*)d_in[11];
    const float* rw   = (const float*)d_in[12];
    const float* rb   = (const float*)d_in[13];
    const float* lg   = (const float*)d_in[14];
    const float* lb   = (const float*)d_in[15];
    const float* pw1  = (const float*)d_in[16];
    const float* pb1  = (const float*)d_in[17];
    const float* pw2  = (const float*)d_in[18];
    const float* pb2  = (const float*)d_in[19];
    const float* pw3  = (const float*)d_in[20];
    const float* pb3  = (const float*)d_in[21];
    float* out = (float*)d_out;

    float* ws     = (float*)d_ws;
    float* h      = ws;                          // 1048576
    float* agg    = ws + 1048576;                // 3 * 1048576
    float* deg    = ws + 4194304;                // 16384
    float* pooled = ws + 4210688;                // 2048
    unsigned int* e2h = (unsigned int*)(ws + 4212800);   // 2097152 u32
    f16* Bp       = (f16*)(ws + 4212800 + 2097152);      // 3 * 266240 f16

    const int* srcp = eidx;
    const int* dstp = eidx + N_EDGES;

    (void)hipMemsetAsync(agg, 0, (size_t)3164224 * sizeof(float), stream);

    k_init   <<<4352, 256, 0, stream>>>(x, Win, bin, dstp, h, deg);
    k_prep_bp<<<390, 256, 0, stream>>>(ew3, eb3, Bp);

    for (int l = 0; l < NLAYERS; l++) {
        float* agg_l = agg + (size_t)l * N_NODES * H;
        k_edge_mlp<<<N_EDGES / 128, 256, 0, stream>>>(ea, ew1 + l * 320, eb1 + l * 64,
                                                      ew2 + l * 4096, eb2 + l * 64,
                                                      (unsigned short*)e2h);
        k_msg     <<<N_EDGES / 128, 256, 0, stream>>>(h, e2h, Bp + (size_t)l * 266240,
                                                      srcp, dstp, agg_l);
        k_node    <<<N_NODES / 64, 256, 0, stream>>>(agg_l, deg, rw + l * 4096, rb + l * 64,
                                                     lg + l * 64, lb + l * 64, h,
                                                     bat, pooled, l == NLAYERS - 1 ? 1 : 0);
    }

    k_head<<<1, 256, 0, stream>>>(pooled, bat, pw1, pb1, pw2, pb2, pw3, pb3, out);
}

// Round 9
// 325.567 us; speedup vs baseline: 1.3972x; 1.0448x over previous
//
#include <hip/hip_runtime.h>
#include <hip/hip_bf16.h>

#define N_NODES 16384
#define N_EDGES 65536
#define NB      32
#define H       64
#define NLAYERS 3
#define NEG     0.1f
#define LN_EPS  1e-5f

typedef _Float16 f16;
typedef _Float16 f16x2 __attribute__((ext_vector_type(2)));
typedef _Float16 f16x8 __attribute__((ext_vector_type(8)));
typedef __fp16   hf16x2 __attribute__((ext_vector_type(2)));
typedef float    f32x16 __attribute__((ext_vector_type(16)));

union F16x8 { f16x8 v; f16x2 p[4]; int4 i4; int2 i2[2]; };
union F16x2U { f16x2 h2; hf16x2 raw; unsigned int u; };
union F16U   { f16 h; unsigned short u; };

__device__ __forceinline__ f16x2 pkrtz(float a, float b) {
    F16x2U t; t.raw = __builtin_amdgcn_cvt_pkrtz(a, b); return t.h2;
}
__device__ __forceinline__ float leaky(float v) { return v > 0.f ? v : NEG * v; }

// ---------------------------------------------------------------- setup: inproj + degree + Bp prep (one dispatch)
// Bp slot = i*8 + ks*2 + oq (i in [0,64]; i==64 = eb3 bias). layer stride 520 slots.
__global__ __launch_bounds__(256) void k_setup(const float* __restrict__ x,
                                               const float* __restrict__ Win,
                                               const float* __restrict__ bin,
                                               const int* __restrict__ dst,
                                               const float* __restrict__ ew3,
                                               const float* __restrict__ eb3,
                                               float* __restrict__ h,
                                               float* __restrict__ deg,
                                               f16* __restrict__ Bp) {
    int bid = blockIdx.x;
    if (bid < 4096) {                       // input projection
        int t = bid * 256 + threadIdx.x;
        int n = t >> 6, j = t & 63;
        const float* xr = x + n * 4;
        const float* wr = Win + j * 4;
        float v = bin[j] + xr[0] * wr[0] + xr[1] * wr[1] + xr[2] * wr[2] + xr[3] * wr[3];
        h[t] = leaky(v);
    } else if (bid < 4352) {                // degree atomics (deg pre-zeroed by memset)
        int e = (bid - 4096) * 256 + threadIdx.x;
        atomicAdd(&deg[dst[e]], 1.0f);
    } else {                                // Bp prep: 390 blocks = 1560 slots
        int tg    = (bid - 4352) * 256 + threadIdx.x;
        int lane  = tg & 63;
        int gslot = tg >> 6;
        int l     = gslot / 520;
        int slot  = gslot - l * 520;
        const float* ew3l = ew3 + (size_t)l * 262144;
        const float* eb3l = eb3 + (size_t)l * 4096;
        int i   = slot >> 3;
        int rem = slot & 7;
        int ks  = rem >> 1;
        int oq  = rem & 1;
        int o   = oq * 32 + (lane & 31);
        int k0  = ks * 16 + (lane >> 5) * 8;
        float v[8];
        if (i < 64) {
            const float* s = ew3l + ((size_t)(i * 64 + o)) * 64 + k0;
            float4 a = ((const float4*)s)[0];
            float4 b = ((const float4*)s)[1];
            v[0] = a.x; v[1] = a.y; v[2] = a.z; v[3] = a.w;
            v[4] = b.x; v[5] = b.y; v[6] = b.z; v[7] = b.w;
        } else {
#pragma unroll
            for (int j = 0; j < 8; j++) v[j] = eb3l[(k0 + j) * 64 + o];
        }
        union { int4 i4; f16 a[8]; } out;
#pragma unroll
        for (int j = 0; j < 8; j++) out.a[j] = (f16)v[j];
        *(int4*)(Bp + (size_t)l * 266240 + (size_t)slot * 512 + lane * 8) = out.i4;
    }
}

// ---------------------------------------------------------------- fused edge-MLP + bilinear MFMA GEMM + scatter
// block = 128 edges, 4 waves (eh, oq); wave = 2 edge-tiles x 32 outputs.
// Prologue computes e2 in-kernel: e1 per-lane (VALU) -> LDS; stage-2 MFMA
// (w2 frags, wave covers its 2 tiles x oq k-half); e2 exchanged via LDS.
// K-loop: R8's proven static register dbuf, barrier-free, 4 acc chains.
#define HS_STRIDE 76   // u16; 152 B rows -> 2-way LDS banks (free)

__device__ __forceinline__ void loadB8(const f16* __restrict__ Bp, int c, int oq, int lane, F16x8* dstB) {
    const f16* base = Bp + (((size_t)(c * 16 + oq)) << 9) + lane * 8;
#pragma unroll
    for (int di = 0; di < 2; di++)
#pragma unroll
        for (int ks = 0; ks < 4; ks++)
            dstB[di * 4 + ks].i4 = *(const int4*)(base + ((di * 8 + ks * 2) << 9));
}
__device__ __forceinline__ void loadB4(const f16* __restrict__ Bp, int oq, int lane, F16x8* dstB) {
    const f16* base = Bp + (((size_t)(512 + oq)) << 9) + lane * 8;
#pragma unroll
    for (int ks = 0; ks < 4; ks++)
        dstB[ks].i4 = *(const int4*)(base + ((ks * 2) << 9));
}

__device__ __forceinline__ void msg_chunk2(int c, const F16x8* __restrict__ B,
                                           const unsigned short* hp0,
                                           const unsigned short* hp1,
                                           const f16x2 (*e2p)[4][4], f32x16* CC) {
    unsigned int rr0 = *(const unsigned int*)(hp0 + 2 * c);
    unsigned int rr1 = *(const unsigned int*)(hp1 + 2 * c);
    F16x2U h00, h01, h10, h11;
    h00.u = __builtin_amdgcn_perm(rr0, rr0, 0x01000100u);
    h10.u = __builtin_amdgcn_perm(rr0, rr0, 0x03020302u);
    h01.u = __builtin_amdgcn_perm(rr1, rr1, 0x01000100u);
    h11.u = __builtin_amdgcn_perm(rr1, rr1, 0x03020302u);
#pragma unroll
    for (int ks = 0; ks < 4; ks++) {
        F16x8 A00, A01, A10, A11;
#pragma unroll
        for (int r = 0; r < 4; r++) {
            A00.p[r] = h00.h2 * e2p[0][ks][r];
            A01.p[r] = h01.h2 * e2p[1][ks][r];
            A10.p[r] = h10.h2 * e2p[0][ks][r];
            A11.p[r] = h11.h2 * e2p[1][ks][r];
        }
        CC[0] = __builtin_amdgcn_mfma_f32_32x32x16_f16(A00.v, B[0 * 4 + ks].v, CC[0], 0, 0, 0);
        CC[1] = __builtin_amdgcn_mfma_f32_32x32x16_f16(A01.v, B[0 * 4 + ks].v, CC[1], 0, 0, 0);
        CC[2] = __builtin_amdgcn_mfma_f32_32x32x16_f16(A10.v, B[1 * 4 + ks].v, CC[2], 0, 0, 0);
        CC[3] = __builtin_amdgcn_mfma_f32_32x32x16_f16(A11.v, B[1 * 4 + ks].v, CC[3], 0, 0, 0);
    }
}

__global__ __launch_bounds__(256, 2) void k_msg(const float* __restrict__ h,
                                                const float* __restrict__ ea,
                                                const float* __restrict__ w1,
                                                const float* __restrict__ b1,
                                                const float* __restrict__ w2,
                                                const float* __restrict__ b2,
                                                const f16* __restrict__ Bp,
                                                const int* __restrict__ src,
                                                const int* __restrict__ dst,
                                                float* __restrict__ agg) {
    __shared__ __align__(16) unsigned short hsL[128 * HS_STRIDE];  // 19.5 KB
    __shared__ __align__(16) unsigned short e1L[128 * 72];         // 18 KB
    __shared__ __align__(16) unsigned short e2L[128 * 72];         // 18 KB
    __shared__ float eas[128 * 8];                                 // 4 KB
    __shared__ int dstL[128];

    const int t    = threadIdx.x;
    const int lane = t & 63;
    const int w    = t >> 6;
    const int eh   = w >> 1, oq = w & 1;
    const int m    = lane & 31;
    const int kp   = lane >> 5;
    const int eb   = blockIdx.x * 128;

    // ---- stage ea rows (5 -> pad 8)
    for (int idx = t; idx < 640; idx += 256) {
        int r = idx / 5, d = idx - r * 5;
        eas[r * 8 + d] = ea[(size_t)eb * 5 + idx];
    }
    // ---- stage h rows (gathered by src, fp32 -> f16): 2 threads per row
    {
        int e    = t >> 1;
        int half = t & 1;
        int nsrc = src[eb + e];
        const float4* hr = (const float4*)(h + (size_t)nsrc * 64 + half * 32);
        unsigned int* hrow = (unsigned int*)hsL + e * (HS_STRIDE / 2) + half * 16;
#pragma unroll
        for (int q = 0; q < 8; q++) {
            float4 v = hr[q];
            F16x2U p0, p1;
            p0.raw = __builtin_amdgcn_cvt_pkrtz(v.x, v.y);
            p1.raw = __builtin_amdgcn_cvt_pkrtz(v.z, v.w);
            hrow[q * 2 + 0] = p0.u;
            hrow[q * 2 + 1] = p1.u;
        }
        if (t < 128) dstL[t] = dst[eb + t];
    }
    __syncthreads();

    // ---- edge-MLP stage 1: e1 = leaky(ea @ w1^T + b1) -> e1L (f16)
    {
        int kk = t & 63;
        int eg = t >> 6;
        float w1r[5];
#pragma unroll
        for (int d = 0; d < 5; d++) w1r[d] = w1[kk * 5 + d];
        float b1r = b1[kk];
#pragma unroll 4
        for (int g = 0; g < 32; g++) {
            int row = eg * 32 + g;
            float4 a4 = *(const float4*)(eas + row * 8);
            float a5 = eas[row * 8 + 4];
            float v = b1r + a4.x * w1r[0] + a4.y * w1r[1] + a4.z * w1r[2] + a4.w * w1r[3] + a5 * w1r[4];
            F16U z; z.h = (f16)leaky(v);
            e1L[row * 72 + kk] = z.u;
        }
    }
    __syncthreads();

    // ---- edge-MLP stage 2 (MFMA): wave (eh, oq) -> tiles eh*2+tt, k_out half oq
    {
        F16x8 W2f[4];
#pragma unroll
        for (int ks = 0; ks < 4; ks++) {
            const float* s = w2 + (size_t)(oq * 32 + m) * 64 + ks * 16 + kp * 8;
            float4 a = ((const float4*)s)[0];
            float4 b = ((const float4*)s)[1];
            W2f[ks].p[0] = pkrtz(a.x, a.y);
            W2f[ks].p[1] = pkrtz(a.z, a.w);
            W2f[ks].p[2] = pkrtz(b.x, b.y);
            W2f[ks].p[3] = pkrtz(b.z, b.w);
        }
        float b2r = b2[oq * 32 + m];
#pragma unroll
        for (int tt = 0; tt < 2; tt++) {
            f32x16 C2 = {0,0,0,0,0,0,0,0,0,0,0,0,0,0,0,0};
#pragma unroll
            for (int ks = 0; ks < 4; ks++) {
                F16x8 A;
                A.i4 = *(const int4*)(e1L + (size_t)((eh * 2 + tt) * 32 + m) * 72 + ks * 16 + kp * 8);
                C2 = __builtin_amdgcn_mfma_f32_32x32x16_f16(A.v, W2f[ks].v, C2, 0, 0, 0);
            }
#pragma unroll
            for (int reg = 0; reg < 16; reg++) {
                int r = (reg & 3) + 8 * (reg >> 2) + 4 * kp;
                F16U z; z.h = (f16)leaky(C2[reg] + b2r);
                e2L[((eh * 2 + tt) * 32 + r) * 72 + oq * 32 + m] = z.u;
            }
        }
    }
    __syncthreads();

    // ---- read e2 A-operand pairs for this wave's 2 tiles (full k)
    f16x2 e2p[2][4][4];
#pragma unroll
    for (int tt = 0; tt < 2; tt++) {
#pragma unroll
        for (int ks = 0; ks < 4; ks++) {
            F16x8 q;
            q.i4 = *(const int4*)(e2L + (size_t)((eh * 2 + tt) * 32 + m) * 72 + ks * 16 + kp * 8);
            e2p[tt][ks][0] = q.p[0]; e2p[tt][ks][1] = q.p[1];
            e2p[tt][ks][2] = q.p[2]; e2p[tt][ks][3] = q.p[3];
        }
    }

    f32x16 CC[4];
#pragma unroll
    for (int q = 0; q < 4; q++)
#pragma unroll
        for (int r = 0; r < 16; r++) CC[q][r] = 0.f;

    const unsigned short* hp0 = hsL + ((eh * 2 + 0) * 32 + m) * HS_STRIDE;
    const unsigned short* hp1 = hsL + ((eh * 2 + 1) * 32 + m) * HS_STRIDE;

    // ---- STATIC double-buffered barrier-free K-loop
    F16x8 B0[8], B1[8];
    loadB8(Bp, 0, oq, lane, B0);
    loadB8(Bp, 1, oq, lane, B1);
    for (int it = 0; it < 15; it++) {
        int c = it * 2;
        msg_chunk2(c,     B0, hp0, hp1, e2p, CC);  loadB8(Bp, c + 2, oq, lane, B0);
        msg_chunk2(c + 1, B1, hp0, hp1, e2p, CC);  loadB8(Bp, c + 3, oq, lane, B1);
    }
    msg_chunk2(30, B0, hp0, hp1, e2p, CC);
    loadB4(Bp, oq, lane, B0);               // bias frags into B0[0..3]
    msg_chunk2(31, B1, hp0, hp1, e2p, CC);

    // ---- bias chunk: A = h itself (k plays the i role), B = eb3 frags
#pragma unroll
    for (int ks = 0; ks < 4; ks++) {
        int koff = (ks * 16 + kp * 8) * 2;
        const char* r0p = (const char*)hsL + (size_t)((eh * 2 + 0) * 32 + m) * (HS_STRIDE * 2) + koff;
        const char* r1p = (const char*)hsL + (size_t)((eh * 2 + 1) * 32 + m) * (HS_STRIDE * 2) + koff;
        F16x8 A0, A1;
        A0.i2[0] = *(const int2*)(r0p); A0.i2[1] = *(const int2*)(r0p + 8);
        A1.i2[0] = *(const int2*)(r1p); A1.i2[1] = *(const int2*)(r1p + 8);
        CC[0] = __builtin_amdgcn_mfma_f32_32x32x16_f16(A0.v, B0[ks].v, CC[0], 0, 0, 0);
        CC[1] = __builtin_amdgcn_mfma_f32_32x32x16_f16(A1.v, B0[ks].v, CC[1], 0, 0, 0);
    }

    // ---- merge i-parity chains, scatter
    int o = oq * 32 + m;
#pragma unroll
    for (int reg = 0; reg < 16; reg++) {
        int r = (reg & 3) + 8 * (reg >> 2) + 4 * kp;
        atomicAdd(&agg[(size_t)dstL[(eh * 2 + 0) * 32 + r] * 64 + o], CC[0][reg] + CC[2][reg]);
    }
#pragma unroll
    for (int reg = 0; reg < 16; reg++) {
        int r = (reg & 3) + 8 * (reg >> 2) + 4 * kp;
        atomicAdd(&agg[(size_t)dstL[(eh * 2 + 1) * 32 + r] * 64 + o], CC[1][reg] + CC[3][reg]);
    }
}

// ---------------------------------------------------------------- node update: MFMA root GEMM + LN + residual (+pool on last)
__global__ __launch_bounds__(256) void k_node(const float* __restrict__ agg,
                                              const float* __restrict__ deg,
                                              const float* __restrict__ rw,
                                              const float* __restrict__ rb,
                                              const float* __restrict__ lg,
                                              const float* __restrict__ lb,
                                              float* __restrict__ h,
                                              const int* __restrict__ batch,
                                              float* __restrict__ pooled,
                                              int last) {
    __shared__ __align__(16) unsigned short hA[64 * 72];
    __shared__ float outL[64][68];
    int t = threadIdx.x;
    int nb = blockIdx.x * 64;
    int lane = t & 63, w = t >> 6;
    int nq = w >> 1, oq = w & 1;
    int m = lane & 31, kp = lane >> 5;

    {
        int r = t >> 2, c0 = (t & 3) * 16;
        const float4* hr = (const float4*)(h + (size_t)(nb + r) * 64 + c0);
        unsigned int* drow = (unsigned int*)hA + r * 36 + c0 / 2;
#pragma unroll
        for (int q = 0; q < 4; q++) {
            float4 v = hr[q];
            F16x2U p0, p1;
            p0.raw = __builtin_amdgcn_cvt_pkrtz(v.x, v.y);
            p1.raw = __builtin_amdgcn_cvt_pkrtz(v.z, v.w);
            drow[q * 2] = p0.u; drow[q * 2 + 1] = p1.u;
        }
    }
    F16x8 Bf[4];
#pragma unroll
    for (int ks = 0; ks < 4; ks++) {
        const float* s = rw + (size_t)(oq * 32 + m) * 64 + ks * 16 + kp * 8;
        float4 a = ((const float4*)s)[0];
        float4 b = ((const float4*)s)[1];
        Bf[ks].p[0] = pkrtz(a.x, a.y);
        Bf[ks].p[1] = pkrtz(a.z, a.w);
        Bf[ks].p[2] = pkrtz(b.x, b.y);
        Bf[ks].p[3] = pkrtz(b.z, b.w);
    }
    __syncthreads();

    f32x16 C = {0,0,0,0,0,0,0,0,0,0,0,0,0,0,0,0};
#pragma unroll
    for (int ks = 0; ks < 4; ks++) {
        F16x8 A;
        A.i4 = *(const int4*)(hA + (size_t)(nq * 32 + m) * 72 + ks * 16 + kp * 8);
        C = __builtin_amdgcn_mfma_f32_32x32x16_f16(A.v, Bf[ks].v, C, 0, 0, 0);
    }

    int o = oq * 32 + m;
#pragma unroll
    for (int reg = 0; reg < 16; reg++) {
        int r = (reg & 3) + 8 * (reg >> 2) + 4 * kp;
        int n = nq * 32 + r;
        outL[n][o] = C[reg] + rb[o] + agg[(size_t)(nb + n) * 64 + o] / fmaxf(deg[nb + n], 1.0f);
    }
    __syncthreads();

    float gj = lg[lane], bj = lb[lane];
    float accp = 0.f;
    int cur = batch[nb + w * 16];
    for (int q = 0; q < 16; q++) {
        int n = w * 16 + q;
        float v = outL[n][lane];
        float mu = v;
#pragma unroll
        for (int msk = 32; msk > 0; msk >>= 1) mu += __shfl_xor(mu, msk);
        mu *= (1.f / 64.f);
        float d = v - mu;
        float var = d * d;
#pragma unroll
        for (int msk = 32; msk > 0; msk >>= 1) var += __shfl_xor(var, msk);
        var *= (1.f / 64.f);
        float ov = d * rsqrtf(var + LN_EPS) * gj + bj;
        float hn = leaky(ov) + h[(size_t)(nb + n) * 64 + lane];
        h[(size_t)(nb + n) * 64 + lane] = hn;
        if (last) {
            int b = batch[nb + n];
            if (b != cur) { atomicAdd(&pooled[cur * 64 + lane], accp); accp = 0.f; cur = b; }
            accp += hn;
        }
    }
    if (last) atomicAdd(&pooled[cur * 64 + lane], accp);
}

// ---------------------------------------------------------------- prediction head (1 block; computes cnt from sorted batch)
__global__ __launch_bounds__(256) void k_head(const float* __restrict__ pooled,
                                              const int* __restrict__ batch,
                                              const float* __restrict__ pw1, const float* __restrict__ pb1,
                                              const float* __restrict__ pw2, const float* __restrict__ pb2,
                                              const float* __restrict__ pw3, const float* __restrict__ pb3,
                                              float* __restrict__ out) {
    __shared__ float cntL[32];
    __shared__ float ps[32][64];
    __shared__ float p1[32][64];
    __shared__ float p2[32][32];
    int t = threadIdx.x;
    if (t < 32) cntL[t] = 0.f;
    __syncthreads();
    {
        const int4* bp4 = (const int4*)(batch + t * 64);
        int cur = batch[t * 64];
        float c = 0.f;
        for (int q = 0; q < 16; q++) {
            int4 b4 = bp4[q];
            int bs[4] = { b4.x, b4.y, b4.z, b4.w };
#pragma unroll
            for (int e = 0; e < 4; e++) {
                if (bs[e] != cur) { atomicAdd(&cntL[cur], c); cur = bs[e]; c = 0.f; }
                c += 1.f;
            }
        }
        atomicAdd(&cntL[cur], c);
    }
    __syncthreads();
    for (int idx = t; idx < 2048; idx += 256) {
        int b = idx >> 6, j = idx & 63;
        ps[b][j] = pooled[idx] / fmaxf(cntL[b], 1.0f);
    }
    __syncthreads();
    for (int idx = t; idx < 2048; idx += 256) {
        int b = idx >> 6, j = idx & 63;
        float v = pb1[j];
#pragma unroll 8
        for (int i = 0; i < 64; i++) v += ps[b][i] * pw1[j * 64 + i];
        p1[b][j] = leaky(v);
    }
    __syncthreads();
    for (int idx = t; idx < 1024; idx += 256) {
        int b = idx >> 5, j = idx & 31;
        float v = pb2[j];
#pragma unroll 8
        for (int i = 0; i < 64; i++) v += p1[b][i] * pw2[j * 64 + i];
        p2[b][j] = leaky(v);
    }
    __syncthreads();
    if (t < 32) {
        float v = pb3[0];
#pragma unroll 8
        for (int i = 0; i < 32; i++) v += p2[t][i] * pw3[i];
        out[t] = v;
    }
}

// ----------------------------------------------------------------
extern "C" void kernel_launch(void* const* d_in, const int* in_sizes, int n_in,
                              void* d_out, int out_size, void* d_ws, size_t ws_size,
                              hipStream_t stream) {
    const float* x    = (const float*)d_in[0];
    const int*   eidx = (const int*)  d_in[1];
    const float* ea   = (const float*)d_in[2];
    const int*   bat  = (const int*)  d_in[3];
    const float* Win  = (const float*)d_in[4];
    const float* bin  = (const float*)d_in[5];
    const float* ew1  = (const float*)d_in[6];
    const float* eb1  = (const float*)d_in[7];
    const float* ew2  = (const float*)d_in[8];
    const float* eb2  = (const float*)d_in[9];
    const float* ew3  = (const float*)d_in[10];
    const float* eb3  = (const float*)d_in[11];
    const float* rw   = (const float*)d_in[12];
    const float* rb   = (const float*)d_in[13];
    const float* lg   = (const float*)d_in[14];
    const float* lb   = (const float*)d_in[15];
    const float* pw1  = (const float*)d_in[16];
    const float* pb1  = (const float*)d_in[17];
    const float* pw2  = (const float*)d_in[18];
    const float* pb2  = (const float*)d_in[19];
    const float* pw3  = (const float*)d_in[20];
    const float* pb3  = (const float*)d_in[21];
    float* out = (float*)d_out;

    float* ws     = (float*)d_ws;
    float* h      = ws;                          // 1048576
    float* agg    = ws + 1048576;                // 3 * 1048576
    float* deg    = ws + 4194304;                // 16384
    float* pooled = ws + 4210688;                // 2048 (+64 pad)
    f16*   Bp     = (f16*)(ws + 4212800);        // 3 * 266240 f16

    const int* srcp = eidx;
    const int* dstp = eidx + N_EDGES;

    // one memset covers agg[3] + deg + pooled (contiguous)
    (void)hipMemsetAsync(agg, 0, (size_t)3164224 * sizeof(float), stream);

    k_setup<<<4742, 256, 0, stream>>>(x, Win, bin, dstp, ew3, eb3, h, deg, Bp);

    for (int l = 0; l < NLAYERS; l++) {
        float* agg_l = agg + (size_t)l * N_NODES * H;
        k_msg <<<N_EDGES / 128, 256, 0, stream>>>(h, ea, ew1 + l * 320, eb1 + l * 64,
                                                  ew2 + l * 4096, eb2 + l * 64,
                                                  Bp + (size_t)l * 266240,
                                                  srcp, dstp, agg_l);
        k_node<<<N_NODES / 64, 256, 0, stream>>>(agg_l, deg, rw + l * 4096, rb + l * 64,
                                                 lg + l * 64, lb + l * 64, h,
                                                 bat, pooled, l == NLAYERS - 1 ? 1 : 0);
    }

    k_head<<<1, 256, 0, stream>>>(pooled, bat, pw1, pb1, pw2, pb2, pw3, pb3, out);
}